// Round 3
// baseline (623.787 us; speedup 1.0000x reference)
//
#include <hip/hip_runtime.h>
#include <math.h>

#define B_      64
#define N_      1024
#define D_      768
#define T_      16
#define SLABS   32          // blocks per batch in pass kernels
#define ROWS_PB 32          // rows per block (N_/SLABS)
#define ROWS_PW 8           // rows per wave (4 waves/block)
#define THR     256

__device__ __forceinline__ float wave_sum(float v) {
    #pragma unroll
    for (int off = 32; off; off >>= 1) v += __shfl_xor(v, off);
    return v;
}

// ---------------- pass 0: saliency + initial argmax partials ----------------
__global__ __launch_bounds__(THR)
void k_sal(const float* __restrict__ feat, float* __restrict__ sal,
           float* __restrict__ rsal, float* __restrict__ mask,
           float* __restrict__ argv, float* __restrict__ args,
           int* __restrict__ argi) {
    const int blk = blockIdx.x, b = blk >> 5, g = blk & 31;
    const int tid = threadIdx.x, wave = tid >> 6, lane = tid & 63;
    __shared__ float s_sal[ROWS_PB];

    const float* fb = feat + ((size_t)b * N_ + (size_t)g * ROWS_PB) * D_;
    const int r0 = wave * ROWS_PW;
    #pragma unroll 2
    for (int r = r0; r < r0 + ROWS_PW; ++r) {
        const float4* rp = (const float4*)(fb + (size_t)r * D_);
        float4 v0 = rp[lane], v1 = rp[lane + 64], v2 = rp[lane + 128];
        float ss = v0.x*v0.x + v0.y*v0.y + v0.z*v0.z + v0.w*v0.w
                 + v1.x*v1.x + v1.y*v1.y + v1.z*v1.z + v1.w*v1.w
                 + v2.x*v2.x + v2.y*v2.y + v2.z*v2.z + v2.w*v2.w;
        ss = wave_sum(ss);
        if (lane == 0) s_sal[r] = sqrtf(ss);
    }
    __syncthreads();

    const int rg = b * N_ + g * ROWS_PB;
    if (tid < ROWS_PB) {
        float n = s_sal[tid];
        sal[rg + tid]  = n;
        rsal[rg + tid] = 1.0f / fmaxf(n, 1e-12f);
        mask[rg + tid] = 1.0f;
    }
    if (wave == 0) {
        float v  = (lane < ROWS_PB) ? s_sal[lane] : -INFINITY;
        float sv = v;
        int   i  = (lane < ROWS_PB) ? (g * ROWS_PB + lane) : 0x7fffffff;
        #pragma unroll
        for (int off = 32; off; off >>= 1) {
            float ov = __shfl_xor(v, off);
            float osv = __shfl_xor(sv, off);
            int   oi = __shfl_xor(i, off);
            if (ov > v || (ov == v && oi < i)) { v = ov; sv = osv; i = oi; }
        }
        if (lane == 0) { argv[b*SLABS+g] = v; args[b*SLABS+g] = sv; argi[b*SLABS+g] = i; }
    }
}

// ---------------- merged per-slot pass ----------------
// Preamble: every block reduces the 32 argmax partials (selection for slot t)
// and loads the selected row directly. Blocks g<4 also reduce the previous
// slot's numerator partials and write out[t-1]. Then the fused sim/weight/
// accumulate/mask-update pass, writing slot-t partials + slot-(t+1) argmax
// partials. Slot-indexed buffers are parity double-buffered by the host.
__global__ __launch_bounds__(THR)
void k_step(const float* __restrict__ feat, const float* __restrict__ sal,
            const float* __restrict__ rsal, float* __restrict__ mask,
            const float* __restrict__ argv_in, const float* __restrict__ args_in,
            const int* __restrict__ argi_in,
            float* __restrict__ argv_out, float* __restrict__ args_out,
            int* __restrict__ argi_out,
            const float* __restrict__ num_in, const float* __restrict__ wsum_in,
            float* __restrict__ num_out, float* __restrict__ wsum_out,
            float* __restrict__ out, int t) {
    const int blk = blockIdx.x, b = blk >> 5, g = blk & 31;
    const int tid = threadIdx.x, wave = tid >> 6, lane = tid & 63;

    __shared__ float s_rsel;
    __shared__ int   s_idx;
    __shared__ float s_ws;
    __shared__ __align__(16) float s_red[4 * D_];   // 12 KiB
    __shared__ float s_wsumW[4];
    __shared__ float s_msal[ROWS_PB];
    __shared__ float s_salL[ROWS_PB];

    // ---- preamble: cross-slab argmax reduce (all blocks, redundant) ----
    if (wave == 0) {
        float v  = (lane < SLABS) ? argv_in[b*SLABS + lane] : -INFINITY;
        float sv = (lane < SLABS) ? args_in[b*SLABS + lane] : 0.f;
        int   i  = (lane < SLABS) ? argi_in[b*SLABS + lane] : 0x7fffffff;
        float w  = (t > 0 && lane < SLABS) ? wsum_in[b*SLABS + lane] : 0.f;
        #pragma unroll
        for (int off = 32; off; off >>= 1) {
            float ov = __shfl_xor(v, off);
            float osv = __shfl_xor(sv, off);
            int   oi = __shfl_xor(i, off);
            w += __shfl_xor(w, off);
            if (ov > v || (ov == v && oi < i)) { v = ov; sv = osv; i = oi; }
        }
        if (lane == 0) { s_idx = i; s_rsel = 1.0f / fmaxf(sv, 1e-12f); s_ws = w; }
    }
    __syncthreads();
    const int idx = s_idx;
    const float rsel = s_rsel;

    // ---- write out[t-1] (4 blocks per batch) ----
    if (t > 0 && g < 4 && tid < 192) {
        const int c = g * 192 + tid;
        float s = 0.f;
        #pragma unroll 8
        for (int gg = 0; gg < SLABS; ++gg)
            s += num_in[((size_t)b * SLABS + gg) * D_ + c];
        out[((size_t)b * T_ + (t-1)) * D_ + c] = s / (s_ws + 1e-8f);
    }

    // ---- load normalized selected-row fragments ----
    const float4* selp = (const float4*)(feat + ((size_t)b * N_ + idx) * D_);
    float4 sel0 = selp[lane], sel1 = selp[lane + 64], sel2 = selp[lane + 128];
    sel0.x *= rsel; sel0.y *= rsel; sel0.z *= rsel; sel0.w *= rsel;
    sel1.x *= rsel; sel1.y *= rsel; sel1.z *= rsel; sel1.w *= rsel;
    sel2.x *= rsel; sel2.y *= rsel; sel2.z *= rsel; sel2.w *= rsel;

    // ---- fused pass over this block's 32 rows ----
    const float* fb = feat + ((size_t)b * N_ + (size_t)g * ROWS_PB) * D_;
    float4 acc0 = {0.f,0.f,0.f,0.f};
    float4 acc1 = {0.f,0.f,0.f,0.f};
    float4 acc2 = {0.f,0.f,0.f,0.f};
    float  wsl  = 0.f;

    const int rbase = b * N_ + g * ROWS_PB;
    const int r0 = wave * ROWS_PW;
    #pragma unroll 2
    for (int r = r0; r < r0 + ROWS_PW; ++r) {
        const float4* rp = (const float4*)(fb + (size_t)r * D_);
        float4 v0 = rp[lane], v1 = rp[lane + 64], v2 = rp[lane + 128];

        float dot = 0.f;
        dot = fmaf(v0.x, sel0.x, dot); dot = fmaf(v0.y, sel0.y, dot);
        dot = fmaf(v0.z, sel0.z, dot); dot = fmaf(v0.w, sel0.w, dot);
        dot = fmaf(v1.x, sel1.x, dot); dot = fmaf(v1.y, sel1.y, dot);
        dot = fmaf(v1.z, sel1.z, dot); dot = fmaf(v1.w, sel1.w, dot);
        dot = fmaf(v2.x, sel2.x, dot); dot = fmaf(v2.y, sel2.y, dot);
        dot = fmaf(v2.z, sel2.z, dot); dot = fmaf(v2.w, sel2.w, dot);
        dot = wave_sum(dot);

        float rs  = rsal[rbase + r];
        float sv  = sal[rbase + r];
        float m   = mask[rbase + r];
        float sim = dot * rs;
        float wr  = (sim > 0.5f) ? (sim * m) : 0.f;
        float nm  = m * (1.0f - fminf(fmaxf(sim, 0.f), 1.f));

        if (lane == 0) {
            mask[rbase + r] = nm;
            s_msal[r] = sv * nm;
            s_salL[r] = sv;
        }

        wsl += wr;
        acc0.x = fmaf(wr, v0.x, acc0.x); acc0.y = fmaf(wr, v0.y, acc0.y);
        acc0.z = fmaf(wr, v0.z, acc0.z); acc0.w = fmaf(wr, v0.w, acc0.w);
        acc1.x = fmaf(wr, v1.x, acc1.x); acc1.y = fmaf(wr, v1.y, acc1.y);
        acc1.z = fmaf(wr, v1.z, acc1.z); acc1.w = fmaf(wr, v1.w, acc1.w);
        acc2.x = fmaf(wr, v2.x, acc2.x); acc2.y = fmaf(wr, v2.y, acc2.y);
        acc2.z = fmaf(wr, v2.z, acc2.z); acc2.w = fmaf(wr, v2.w, acc2.w);
    }

    {
        float4* red = (float4*)(s_red + wave * D_);
        red[lane]       = acc0;
        red[lane + 64]  = acc1;
        red[lane + 128] = acc2;
        if (lane == 0) s_wsumW[wave] = wsl;
    }
    __syncthreads();

    for (int c = tid; c < D_; c += THR) {
        float s = s_red[c] + s_red[D_ + c] + s_red[2*D_ + c] + s_red[3*D_ + c];
        num_out[((size_t)b * SLABS + g) * D_ + c] = s;
    }
    if (tid == 0)
        wsum_out[b*SLABS+g] = s_wsumW[0] + s_wsumW[1] + s_wsumW[2] + s_wsumW[3];

    if (wave == 0) {
        float v  = (lane < ROWS_PB) ? s_msal[lane] : -INFINITY;
        float sv = (lane < ROWS_PB) ? s_salL[lane] : 0.f;
        int   i  = (lane < ROWS_PB) ? (g * ROWS_PB + lane) : 0x7fffffff;
        #pragma unroll
        for (int off = 32; off; off >>= 1) {
            float ov = __shfl_xor(v, off);
            float osv = __shfl_xor(sv, off);
            int   oi = __shfl_xor(i, off);
            if (ov > v || (ov == v && oi < i)) { v = ov; sv = osv; i = oi; }
        }
        if (lane == 0) { argv_out[b*SLABS+g] = v; args_out[b*SLABS+g] = sv; argi_out[b*SLABS+g] = i; }
    }
}

// ---------------- final: write out[T-1] ----------------
__global__ __launch_bounds__(192)
void k_final(const float* __restrict__ num_in, const float* __restrict__ wsum_in,
             float* __restrict__ out) {
    const int b = blockIdx.x >> 2, q = blockIdx.x & 3;
    const int tid = threadIdx.x, lane = tid & 63;
    __shared__ float s_ws;
    if (tid < 64) {
        float w = (lane < SLABS) ? wsum_in[b*SLABS + lane] : 0.f;
        #pragma unroll
        for (int off = 32; off; off >>= 1) w += __shfl_xor(w, off);
        if (lane == 0) s_ws = w;
    }
    __syncthreads();
    const int c = q * 192 + tid;
    float s = 0.f;
    #pragma unroll 8
    for (int gg = 0; gg < SLABS; ++gg)
        s += num_in[((size_t)b * SLABS + gg) * D_ + c];
    out[((size_t)b * T_ + (T_-1)) * D_ + c] = s / (s_ws + 1e-8f);
}

// ---------------- fallback kernels (round-2 path) ----------------
__global__ __launch_bounds__(THR)
void k_fused(const float* __restrict__ feat, const float* __restrict__ sel,
             const float* __restrict__ sal, const float* __restrict__ rsal,
             float* __restrict__ mask, float* __restrict__ num,
             float* __restrict__ wsum, float* __restrict__ argv,
             float* __restrict__ args, int* __restrict__ argi) {
    const int blk = blockIdx.x, b = blk >> 5, g = blk & 31;
    const int tid = threadIdx.x, wave = tid >> 6, lane = tid & 63;
    __shared__ __align__(16) float s_red[4 * D_];
    __shared__ float s_wsum[4];
    __shared__ float s_msal[ROWS_PB];
    __shared__ float s_salL[ROWS_PB];
    const float* fb = feat + ((size_t)b * N_ + (size_t)g * ROWS_PB) * D_;
    const float4* selp = (const float4*)(sel + (size_t)b * D_);
    float4 sel0 = selp[lane], sel1 = selp[lane + 64], sel2 = selp[lane + 128];
    float4 acc0 = {0.f,0.f,0.f,0.f}, acc1 = {0.f,0.f,0.f,0.f}, acc2 = {0.f,0.f,0.f,0.f};
    float wsl = 0.f;
    const int rbase = b * N_ + g * ROWS_PB;
    const int r0 = wave * ROWS_PW;
    #pragma unroll 2
    for (int r = r0; r < r0 + ROWS_PW; ++r) {
        const float4* rp = (const float4*)(fb + (size_t)r * D_);
        float4 v0 = rp[lane], v1 = rp[lane + 64], v2 = rp[lane + 128];
        float dot = 0.f;
        dot = fmaf(v0.x, sel0.x, dot); dot = fmaf(v0.y, sel0.y, dot);
        dot = fmaf(v0.z, sel0.z, dot); dot = fmaf(v0.w, sel0.w, dot);
        dot = fmaf(v1.x, sel1.x, dot); dot = fmaf(v1.y, sel1.y, dot);
        dot = fmaf(v1.z, sel1.z, dot); dot = fmaf(v1.w, sel1.w, dot);
        dot = fmaf(v2.x, sel2.x, dot); dot = fmaf(v2.y, sel2.y, dot);
        dot = fmaf(v2.z, sel2.z, dot); dot = fmaf(v2.w, sel2.w, dot);
        dot = wave_sum(dot);
        float rs = rsal[rbase + r], sv = sal[rbase + r], m = mask[rbase + r];
        float sim = dot * rs;
        float wr = (sim > 0.5f) ? (sim * m) : 0.f;
        float nm = m * (1.0f - fminf(fmaxf(sim, 0.f), 1.f));
        if (lane == 0) { mask[rbase + r] = nm; s_msal[r] = sv * nm; s_salL[r] = sv; }
        wsl += wr;
        acc0.x = fmaf(wr, v0.x, acc0.x); acc0.y = fmaf(wr, v0.y, acc0.y);
        acc0.z = fmaf(wr, v0.z, acc0.z); acc0.w = fmaf(wr, v0.w, acc0.w);
        acc1.x = fmaf(wr, v1.x, acc1.x); acc1.y = fmaf(wr, v1.y, acc1.y);
        acc1.z = fmaf(wr, v1.z, acc1.z); acc1.w = fmaf(wr, v1.w, acc1.w);
        acc2.x = fmaf(wr, v2.x, acc2.x); acc2.y = fmaf(wr, v2.y, acc2.y);
        acc2.z = fmaf(wr, v2.z, acc2.z); acc2.w = fmaf(wr, v2.w, acc2.w);
    }
    {
        float4* red = (float4*)(s_red + wave * D_);
        red[lane] = acc0; red[lane + 64] = acc1; red[lane + 128] = acc2;
        if (lane == 0) s_wsum[wave] = wsl;
    }
    __syncthreads();
    for (int c = tid; c < D_; c += THR) {
        float s = s_red[c] + s_red[D_ + c] + s_red[2*D_ + c] + s_red[3*D_ + c];
        num[((size_t)b * SLABS + g) * D_ + c] = s;
    }
    if (tid == 0) wsum[b*SLABS+g] = s_wsum[0] + s_wsum[1] + s_wsum[2] + s_wsum[3];
    if (wave == 0) {
        float v  = (lane < ROWS_PB) ? s_msal[lane] : -INFINITY;
        float sv = (lane < ROWS_PB) ? s_salL[lane] : 0.f;
        int   i  = (lane < ROWS_PB) ? (g * ROWS_PB + lane) : 0x7fffffff;
        #pragma unroll
        for (int off = 32; off; off >>= 1) {
            float ov = __shfl_xor(v, off);
            float osv = __shfl_xor(sv, off);
            int   oi = __shfl_xor(i, off);
            if (ov > v || (ov == v && oi < i)) { v = ov; sv = osv; i = oi; }
        }
        if (lane == 0) { argv[b*SLABS+g] = v; args[b*SLABS+g] = sv; argi[b*SLABS+g] = i; }
    }
}

__global__ __launch_bounds__(192)
void k_out(const float* __restrict__ feat, const float* __restrict__ num,
           const float* __restrict__ wsumA, const float* __restrict__ argv,
           const float* __restrict__ args, const int* __restrict__ argi,
           float* __restrict__ sel, float* __restrict__ out, int t) {
    const int b = blockIdx.x >> 2, q = blockIdx.x & 3;
    const int tid = threadIdx.x, lane = tid & 63;
    __shared__ float s_rsel;
    __shared__ int   s_idx;
    __shared__ float s_ws;
    if (tid < 64) {
        float v  = (lane < SLABS) ? argv[b*SLABS + lane] : -INFINITY;
        float sv = (lane < SLABS) ? args[b*SLABS + lane] : 0.f;
        int   i  = (lane < SLABS) ? argi[b*SLABS + lane] : 0x7fffffff;
        float w  = (lane < SLABS) ? wsumA[b*SLABS + lane] : 0.f;
        #pragma unroll
        for (int off = 32; off; off >>= 1) {
            float ov = __shfl_xor(v, off);
            float osv = __shfl_xor(sv, off);
            int   oi = __shfl_xor(i, off);
            w += __shfl_xor(w, off);
            if (ov > v || (ov == v && oi < i)) { v = ov; sv = osv; i = oi; }
        }
        if (lane == 0) { s_idx = i; s_rsel = 1.0f / fmaxf(sv, 1e-12f); s_ws = w; }
    }
    __syncthreads();
    const int c = q * 192 + tid;
    if (t >= 0) {
        float s = 0.f;
        #pragma unroll 8
        for (int g = 0; g < SLABS; ++g)
            s += num[((size_t)b * SLABS + g) * D_ + c];
        out[((size_t)b * T_ + t) * D_ + c] = s / (s_ws + 1e-8f);
    }
    sel[(size_t)b * D_ + c] = feat[((size_t)b * N_ + s_idx) * D_ + c] * s_rsel;
}

// ---------------- fallback: single-kernel mono ----------------
__global__ __launch_bounds__(1024, 1)
void greedy_mono(const float* __restrict__ feat, float* __restrict__ out) {
    const int b = blockIdx.x, tid = threadIdx.x, wave = tid >> 6, lane = tid & 63;
    __shared__ float s_mask[N_], s_sal[N_], s_rsal[N_];
    __shared__ __align__(16) float s_sel[D_];
    __shared__ __align__(16) float s_red[16 * D_];
    __shared__ float s_wsum[16], s_argv[16];
    __shared__ int s_argi[16], s_idx;
    const float* fb = feat + (size_t)b * N_ * D_;
    {
        const int r0 = wave * 64;
        for (int r = r0; r < r0 + 64; ++r) {
            const float4* rp = (const float4*)(fb + (size_t)r * D_);
            float4 v0 = rp[lane], v1 = rp[lane+64], v2 = rp[lane+128];
            float ss = v0.x*v0.x+v0.y*v0.y+v0.z*v0.z+v0.w*v0.w
                     + v1.x*v1.x+v1.y*v1.y+v1.z*v1.z+v1.w*v1.w
                     + v2.x*v2.x+v2.y*v2.y+v2.z*v2.z+v2.w*v2.w;
            ss = wave_sum(ss);
            if (lane == 0) { float n = sqrtf(ss); s_sal[r]=n; s_rsal[r]=1.f/fmaxf(n,1e-12f); s_mask[r]=1.f; }
        }
    }
    __syncthreads();
    for (int t = 0; t < T_; ++t) {
        {
            float bv = s_sal[tid] * s_mask[tid]; int bi = tid;
            #pragma unroll
            for (int off = 32; off; off >>= 1) {
                float ov = __shfl_xor(bv, off); int oi = __shfl_xor(bi, off);
                if (ov > bv || (ov == bv && oi < bi)) { bv = ov; bi = oi; }
            }
            if (lane == 0) { s_argv[wave] = bv; s_argi[wave] = bi; }
        }
        __syncthreads();
        if (tid == 0) {
            float best = s_argv[0]; int besti = s_argi[0];
            #pragma unroll
            for (int w = 1; w < 16; ++w) {
                float v = s_argv[w]; int i = s_argi[w];
                if (v > best || (v == best && i < besti)) { best = v; besti = i; }
            }
            s_idx = besti;
        }
        __syncthreads();
        const int idx = s_idx;
        if (tid < D_) s_sel[tid] = fb[(size_t)idx*D_+tid] * (1.f/fmaxf(s_sal[idx],1e-12f));
        __syncthreads();
        const float4* selp = (const float4*)s_sel;
        float4 sel0 = selp[lane], sel1 = selp[lane+64], sel2 = selp[lane+128];
        float4 a0={0,0,0,0}, a1={0,0,0,0}, a2={0,0,0,0}; float wsl=0.f;
        const int r0 = wave * 64;
        for (int r = r0; r < r0 + 64; ++r) {
            const float4* rp = (const float4*)(fb + (size_t)r * D_);
            float4 v0 = rp[lane], v1 = rp[lane+64], v2 = rp[lane+128];
            float dot = 0.f;
            dot=fmaf(v0.x,sel0.x,dot); dot=fmaf(v0.y,sel0.y,dot); dot=fmaf(v0.z,sel0.z,dot); dot=fmaf(v0.w,sel0.w,dot);
            dot=fmaf(v1.x,sel1.x,dot); dot=fmaf(v1.y,sel1.y,dot); dot=fmaf(v1.z,sel1.z,dot); dot=fmaf(v1.w,sel1.w,dot);
            dot=fmaf(v2.x,sel2.x,dot); dot=fmaf(v2.y,sel2.y,dot); dot=fmaf(v2.z,sel2.z,dot); dot=fmaf(v2.w,sel2.w,dot);
            dot = wave_sum(dot);
            float sim = dot * s_rsal[r], m = s_mask[r];
            float wr = (sim > 0.5f) ? (sim * m) : 0.f;
            if (lane == 0) s_mask[r] = m * (1.f - fminf(fmaxf(sim,0.f),1.f));
            wsl += wr;
            a0.x=fmaf(wr,v0.x,a0.x); a0.y=fmaf(wr,v0.y,a0.y); a0.z=fmaf(wr,v0.z,a0.z); a0.w=fmaf(wr,v0.w,a0.w);
            a1.x=fmaf(wr,v1.x,a1.x); a1.y=fmaf(wr,v1.y,a1.y); a1.z=fmaf(wr,v1.z,a1.z); a1.w=fmaf(wr,v1.w,a1.w);
            a2.x=fmaf(wr,v2.x,a2.x); a2.y=fmaf(wr,v2.y,a2.y); a2.z=fmaf(wr,v2.z,a2.z); a2.w=fmaf(wr,v2.w,a2.w);
        }
        {
            float4* red = (float4*)(s_red + wave * D_);
            red[lane]=a0; red[lane+64]=a1; red[lane+128]=a2;
            if (lane == 0) s_wsum[wave] = wsl;
        }
        __syncthreads();
        if (tid < D_) {
            float s = 0.f, den = 0.f;
            #pragma unroll
            for (int w = 0; w < 16; ++w) { s += s_red[w*D_+tid]; den += s_wsum[w]; }
            out[((size_t)b*T_+t)*D_+tid] = s / (den + 1e-8f);
        }
        __syncthreads();
    }
}

extern "C" void kernel_launch(void* const* d_in, const int* in_sizes, int n_in,
                              void* d_out, int out_size, void* d_ws, size_t ws_size,
                              hipStream_t stream) {
    const float* feat = (const float*)d_in[0];
    float* out = (float*)d_out;
    (void)in_sizes; (void)n_in; (void)out_size;

    const size_t n_sal = (size_t)B_ * N_;
    const size_t n_arg = (size_t)B_ * SLABS;
    const size_t n_sel = (size_t)B_ * D_;
    const size_t n_num = (size_t)B_ * SLABS * D_;

    // full (merged) path: double-buffered slot scratch
    const size_t need_full = (3*n_sal + 2*4*n_arg + 2*n_num) * sizeof(float);
    // round-2 path
    const size_t need_r2   = (3*n_sal + 4*n_arg + n_sel + n_num) * sizeof(float);

    if (ws_size >= need_full) {
        float* p = (float*)d_ws;
        float* sal  = p;                 p += n_sal;
        float* rsal = p;                 p += n_sal;
        float* mask = p;                 p += n_sal;
        float* argv[2]; float* args[2]; int* argi[2]; float* wsb[2]; float* num[2];
        for (int k = 0; k < 2; ++k) {
            argv[k] = p;        p += n_arg;
            args[k] = p;        p += n_arg;
            argi[k] = (int*)p;  p += n_arg;
            wsb[k]  = p;        p += n_arg;
        }
        num[0] = p; p += n_num;
        num[1] = p; p += n_num;

        k_sal<<<B_*SLABS, THR, 0, stream>>>(feat, sal, rsal, mask,
                                            argv[0], args[0], argi[0]);
        for (int t = 0; t < T_; ++t) {
            const int pi = t & 1, po = (t + 1) & 1;
            k_step<<<B_*SLABS, THR, 0, stream>>>(
                feat, sal, rsal, mask,
                argv[pi], args[pi], argi[pi],
                argv[po], args[po], argi[po],
                num[po], wsb[po],          // slot t-1 partials ((t-1)&1 == po)
                num[pi], wsb[pi],          // slot t partials
                out, t);
        }
        k_final<<<B_*4, 192, 0, stream>>>(num[(T_-1)&1], wsb[(T_-1)&1], out);
        return;
    }

    if (ws_size >= need_r2) {
        float* p = (float*)d_ws;
        float* sal  = p;            p += n_sal;
        float* rsal = p;            p += n_sal;
        float* mask = p;            p += n_sal;
        float* argv = p;            p += n_arg;
        float* args = p;            p += n_arg;
        int*   argi = (int*)p;      p += n_arg;
        float* wsum = p;            p += n_arg;
        float* sel  = p;            p += n_sel;
        float* num  = p;            p += n_num;

        k_sal<<<B_*SLABS, THR, 0, stream>>>(feat, sal, rsal, mask, argv, args, argi);
        k_out<<<B_*4, 192, 0, stream>>>(feat, num, wsum, argv, args, argi, sel, out, -1);
        for (int t = 0; t < T_; ++t) {
            k_fused<<<B_*SLABS, THR, 0, stream>>>(feat, sel, sal, rsal, mask,
                                                  num, wsum, argv, args, argi);
            k_out<<<B_*4, 192, 0, stream>>>(feat, num, wsum, argv, args, argi, sel, out, t);
        }
        return;
    }

    greedy_mono<<<B_, 1024, 0, stream>>>(feat, out);
}

// Round 4
// 484.667 us; speedup vs baseline: 1.2870x; 1.2870x over previous
//
#include <hip/hip_runtime.h>
#include <hip/hip_fp16.h>
#include <math.h>

#define B_      64
#define N_      1024
#define D_      768
#define T_      16
#define SLABS   32          // blocks per batch in pass kernels
#define ROWS_PB 32          // rows per block (N_/SLABS)
#define ROWS_PW 8           // rows per wave (4 waves/block)
#define THR     256

__device__ __forceinline__ float wave_sum(float v) {
    #pragma unroll
    for (int off = 32; off; off >>= 1) v += __shfl_xor(v, off);
    return v;
}

__device__ __forceinline__ uint2 pack4(float4 v) {
    __half2 h0 = __float22half2_rn(make_float2(v.x, v.y));
    __half2 h1 = __float22half2_rn(make_float2(v.z, v.w));
    uint2 u;
    u.x = *(unsigned int*)&h0;
    u.y = *(unsigned int*)&h1;
    return u;
}

__device__ __forceinline__ float4 unpack4(uint2 u) {
    __half2 h0 = *(__half2*)&u.x;
    __half2 h1 = *(__half2*)&u.y;
    float2 a = __half22float2(h0);
    float2 b = __half22float2(h1);
    float4 v; v.x = a.x; v.y = a.y; v.z = b.x; v.w = b.y;
    return v;
}

// ---------------- pass 0 (fp16 path): saliency + fp16 copy + argmax partials ----------------
__global__ __launch_bounds__(THR)
void k_sal16(const float* __restrict__ feat, ushort* __restrict__ f16,
             float* __restrict__ sal, float* __restrict__ rsal,
             float* __restrict__ mask, float* __restrict__ argv,
             float* __restrict__ args, int* __restrict__ argi) {
    const int blk = blockIdx.x, b = blk >> 5, g = blk & 31;
    const int tid = threadIdx.x, wave = tid >> 6, lane = tid & 63;
    __shared__ float s_sal[ROWS_PB];

    const size_t row0 = (size_t)b * N_ + (size_t)g * ROWS_PB;
    const int r0 = wave * ROWS_PW;
    #pragma unroll 2
    for (int r = r0; r < r0 + ROWS_PW; ++r) {
        const float4* rp = (const float4*)(feat + (row0 + r) * D_);
        float4 v0 = rp[lane], v1 = rp[lane + 64], v2 = rp[lane + 128];
        uint2* wp = (uint2*)(f16 + (row0 + r) * D_);
        wp[lane]       = pack4(v0);
        wp[lane + 64]  = pack4(v1);
        wp[lane + 128] = pack4(v2);
        float ss = v0.x*v0.x + v0.y*v0.y + v0.z*v0.z + v0.w*v0.w
                 + v1.x*v1.x + v1.y*v1.y + v1.z*v1.z + v1.w*v1.w
                 + v2.x*v2.x + v2.y*v2.y + v2.z*v2.z + v2.w*v2.w;
        ss = wave_sum(ss);
        if (lane == 0) s_sal[r] = sqrtf(ss);
    }
    __syncthreads();

    const int rg = b * N_ + g * ROWS_PB;
    if (tid < ROWS_PB) {
        float n = s_sal[tid];
        sal[rg + tid]  = n;
        rsal[rg + tid] = 1.0f / fmaxf(n, 1e-12f);
        mask[rg + tid] = 1.0f;
    }
    if (wave == 0) {
        float v  = (lane < ROWS_PB) ? s_sal[lane] : -INFINITY;
        float sv = v;
        int   i  = (lane < ROWS_PB) ? (g * ROWS_PB + lane) : 0x7fffffff;
        #pragma unroll
        for (int off = 32; off; off >>= 1) {
            float ov = __shfl_xor(v, off);
            float osv = __shfl_xor(sv, off);
            int   oi = __shfl_xor(i, off);
            if (ov > v || (ov == v && oi < i)) { v = ov; sv = osv; i = oi; }
        }
        if (lane == 0) { argv[b*SLABS+g] = v; args[b*SLABS+g] = sv; argi[b*SLABS+g] = i; }
    }
}

// ---------------- per-slot main pass (fp16 reads) ----------------
__global__ __launch_bounds__(THR)
void k_fused16(const ushort* __restrict__ f16, const float* __restrict__ sel,
               const float* __restrict__ sal, const float* __restrict__ rsal,
               float* __restrict__ mask, float* __restrict__ num,
               float* __restrict__ wsum, float* __restrict__ argv,
               float* __restrict__ args, int* __restrict__ argi) {
    const int blk = blockIdx.x, b = blk >> 5, g = blk & 31;
    const int tid = threadIdx.x, wave = tid >> 6, lane = tid & 63;

    __shared__ __align__(16) float s_red[4 * D_];   // 12 KiB
    __shared__ float s_wsum[4];
    __shared__ float s_msal[ROWS_PB];
    __shared__ float s_salL[ROWS_PB];

    const size_t row0 = (size_t)b * N_ + (size_t)g * ROWS_PB;
    const float4* selp = (const float4*)(sel + (size_t)b * D_);
    float4 sel0 = selp[lane], sel1 = selp[lane + 64], sel2 = selp[lane + 128];

    float4 acc0 = {0.f,0.f,0.f,0.f};
    float4 acc1 = {0.f,0.f,0.f,0.f};
    float4 acc2 = {0.f,0.f,0.f,0.f};
    float  wsl  = 0.f;

    const int rbase = b * N_ + g * ROWS_PB;
    const int r0 = wave * ROWS_PW;
    #pragma unroll 2
    for (int r = r0; r < r0 + ROWS_PW; ++r) {
        const uint2* rp = (const uint2*)(f16 + (row0 + r) * D_);
        uint2 u0 = rp[lane], u1 = rp[lane + 64], u2 = rp[lane + 128];
        float4 v0 = unpack4(u0), v1 = unpack4(u1), v2 = unpack4(u2);

        float dot = 0.f;
        dot = fmaf(v0.x, sel0.x, dot); dot = fmaf(v0.y, sel0.y, dot);
        dot = fmaf(v0.z, sel0.z, dot); dot = fmaf(v0.w, sel0.w, dot);
        dot = fmaf(v1.x, sel1.x, dot); dot = fmaf(v1.y, sel1.y, dot);
        dot = fmaf(v1.z, sel1.z, dot); dot = fmaf(v1.w, sel1.w, dot);
        dot = fmaf(v2.x, sel2.x, dot); dot = fmaf(v2.y, sel2.y, dot);
        dot = fmaf(v2.z, sel2.z, dot); dot = fmaf(v2.w, sel2.w, dot);
        dot = wave_sum(dot);

        float rs  = rsal[rbase + r];
        float sv  = sal[rbase + r];
        float m   = mask[rbase + r];
        float sim = dot * rs;
        float wr  = (sim > 0.5f) ? (sim * m) : 0.f;
        float nm  = m * (1.0f - fminf(fmaxf(sim, 0.f), 1.f));

        if (lane == 0) {
            mask[rbase + r] = nm;
            s_msal[r] = sv * nm;
            s_salL[r] = sv;
        }

        wsl += wr;
        acc0.x = fmaf(wr, v0.x, acc0.x); acc0.y = fmaf(wr, v0.y, acc0.y);
        acc0.z = fmaf(wr, v0.z, acc0.z); acc0.w = fmaf(wr, v0.w, acc0.w);
        acc1.x = fmaf(wr, v1.x, acc1.x); acc1.y = fmaf(wr, v1.y, acc1.y);
        acc1.z = fmaf(wr, v1.z, acc1.z); acc1.w = fmaf(wr, v1.w, acc1.w);
        acc2.x = fmaf(wr, v2.x, acc2.x); acc2.y = fmaf(wr, v2.y, acc2.y);
        acc2.z = fmaf(wr, v2.z, acc2.z); acc2.w = fmaf(wr, v2.w, acc2.w);
    }

    {
        float4* red = (float4*)(s_red + wave * D_);
        red[lane]       = acc0;
        red[lane + 64]  = acc1;
        red[lane + 128] = acc2;
        if (lane == 0) s_wsum[wave] = wsl;
    }
    __syncthreads();

    for (int c = tid; c < D_; c += THR) {
        float s = s_red[c] + s_red[D_ + c] + s_red[2*D_ + c] + s_red[3*D_ + c];
        num[((size_t)b * SLABS + g) * D_ + c] = s;
    }
    if (tid == 0)
        wsum[b*SLABS+g] = s_wsum[0] + s_wsum[1] + s_wsum[2] + s_wsum[3];

    if (wave == 0) {
        float v  = (lane < ROWS_PB) ? s_msal[lane] : -INFINITY;
        float sv = (lane < ROWS_PB) ? s_salL[lane] : 0.f;
        int   i  = (lane < ROWS_PB) ? (g * ROWS_PB + lane) : 0x7fffffff;
        #pragma unroll
        for (int off = 32; off; off >>= 1) {
            float ov = __shfl_xor(v, off);
            float osv = __shfl_xor(sv, off);
            int   oi = __shfl_xor(i, off);
            if (ov > v || (ov == v && oi < i)) { v = ov; sv = osv; i = oi; }
        }
        if (lane == 0) { argv[b*SLABS+g] = v; args[b*SLABS+g] = sv; argi[b*SLABS+g] = i; }
    }
}

// ---------------- per-slot reduce: write out[t], compute next sel (exact f32) ----------------
__global__ __launch_bounds__(192)
void k_out(const float* __restrict__ feat, const float* __restrict__ num,
           const float* __restrict__ wsumA, const float* __restrict__ argv,
           const float* __restrict__ args, const int* __restrict__ argi,
           float* __restrict__ sel, float* __restrict__ out, int t) {
    const int b = blockIdx.x >> 2, q = blockIdx.x & 3;
    const int tid = threadIdx.x, lane = tid & 63;

    __shared__ float s_rsel;
    __shared__ int   s_idx;
    __shared__ float s_ws;

    if (tid < 64) {
        float v  = (lane < SLABS) ? argv[b*SLABS + lane] : -INFINITY;
        float sv = (lane < SLABS) ? args[b*SLABS + lane] : 0.f;
        int   i  = (lane < SLABS) ? argi[b*SLABS + lane] : 0x7fffffff;
        float w  = (lane < SLABS) ? wsumA[b*SLABS + lane] : 0.f;
        #pragma unroll
        for (int off = 32; off; off >>= 1) {
            float ov = __shfl_xor(v, off);
            float osv = __shfl_xor(sv, off);
            int   oi = __shfl_xor(i, off);
            w += __shfl_xor(w, off);
            if (ov > v || (ov == v && oi < i)) { v = ov; sv = osv; i = oi; }
        }
        if (lane == 0) {
            s_idx  = i;
            s_rsel = 1.0f / fmaxf(sv, 1e-12f);
            s_ws   = w;
        }
    }
    __syncthreads();

    const int c = q * 192 + tid;
    if (t >= 0) {
        float s = 0.f;
        #pragma unroll 8
        for (int g = 0; g < SLABS; ++g)
            s += num[((size_t)b * SLABS + g) * D_ + c];
        out[((size_t)b * T_ + t) * D_ + c] = s / (s_ws + 1e-8f);
    }
    sel[(size_t)b * D_ + c] = feat[((size_t)b * N_ + s_idx) * D_ + c] * s_rsel;
}

// ---------------- f32 fallback path (round-2, proven) ----------------
__global__ __launch_bounds__(THR)
void k_sal(const float* __restrict__ feat, float* __restrict__ sal,
           float* __restrict__ rsal, float* __restrict__ mask,
           float* __restrict__ argv, float* __restrict__ args,
           int* __restrict__ argi) {
    const int blk = blockIdx.x, b = blk >> 5, g = blk & 31;
    const int tid = threadIdx.x, wave = tid >> 6, lane = tid & 63;
    __shared__ float s_sal[ROWS_PB];
    const float* fb = feat + ((size_t)b * N_ + (size_t)g * ROWS_PB) * D_;
    const int r0 = wave * ROWS_PW;
    #pragma unroll 2
    for (int r = r0; r < r0 + ROWS_PW; ++r) {
        const float4* rp = (const float4*)(fb + (size_t)r * D_);
        float4 v0 = rp[lane], v1 = rp[lane + 64], v2 = rp[lane + 128];
        float ss = v0.x*v0.x + v0.y*v0.y + v0.z*v0.z + v0.w*v0.w
                 + v1.x*v1.x + v1.y*v1.y + v1.z*v1.z + v1.w*v1.w
                 + v2.x*v2.x + v2.y*v2.y + v2.z*v2.z + v2.w*v2.w;
        ss = wave_sum(ss);
        if (lane == 0) s_sal[r] = sqrtf(ss);
    }
    __syncthreads();
    const int rg = b * N_ + g * ROWS_PB;
    if (tid < ROWS_PB) {
        float n = s_sal[tid];
        sal[rg + tid]  = n;
        rsal[rg + tid] = 1.0f / fmaxf(n, 1e-12f);
        mask[rg + tid] = 1.0f;
    }
    if (wave == 0) {
        float v  = (lane < ROWS_PB) ? s_sal[lane] : -INFINITY;
        float sv = v;
        int   i  = (lane < ROWS_PB) ? (g * ROWS_PB + lane) : 0x7fffffff;
        #pragma unroll
        for (int off = 32; off; off >>= 1) {
            float ov = __shfl_xor(v, off);
            float osv = __shfl_xor(sv, off);
            int   oi = __shfl_xor(i, off);
            if (ov > v || (ov == v && oi < i)) { v = ov; sv = osv; i = oi; }
        }
        if (lane == 0) { argv[b*SLABS+g] = v; args[b*SLABS+g] = sv; argi[b*SLABS+g] = i; }
    }
}

__global__ __launch_bounds__(THR)
void k_fused(const float* __restrict__ feat, const float* __restrict__ sel,
             const float* __restrict__ sal, const float* __restrict__ rsal,
             float* __restrict__ mask, float* __restrict__ num,
             float* __restrict__ wsum, float* __restrict__ argv,
             float* __restrict__ args, int* __restrict__ argi) {
    const int blk = blockIdx.x, b = blk >> 5, g = blk & 31;
    const int tid = threadIdx.x, wave = tid >> 6, lane = tid & 63;
    __shared__ __align__(16) float s_red[4 * D_];
    __shared__ float s_wsum[4];
    __shared__ float s_msal[ROWS_PB];
    __shared__ float s_salL[ROWS_PB];
    const float* fb = feat + ((size_t)b * N_ + (size_t)g * ROWS_PB) * D_;
    const float4* selp = (const float4*)(sel + (size_t)b * D_);
    float4 sel0 = selp[lane], sel1 = selp[lane + 64], sel2 = selp[lane + 128];
    float4 acc0 = {0.f,0.f,0.f,0.f}, acc1 = {0.f,0.f,0.f,0.f}, acc2 = {0.f,0.f,0.f,0.f};
    float wsl = 0.f;
    const int rbase = b * N_ + g * ROWS_PB;
    const int r0 = wave * ROWS_PW;
    #pragma unroll 2
    for (int r = r0; r < r0 + ROWS_PW; ++r) {
        const float4* rp = (const float4*)(fb + (size_t)r * D_);
        float4 v0 = rp[lane], v1 = rp[lane + 64], v2 = rp[lane + 128];
        float dot = 0.f;
        dot = fmaf(v0.x, sel0.x, dot); dot = fmaf(v0.y, sel0.y, dot);
        dot = fmaf(v0.z, sel0.z, dot); dot = fmaf(v0.w, sel0.w, dot);
        dot = fmaf(v1.x, sel1.x, dot); dot = fmaf(v1.y, sel1.y, dot);
        dot = fmaf(v1.z, sel1.z, dot); dot = fmaf(v1.w, sel1.w, dot);
        dot = fmaf(v2.x, sel2.x, dot); dot = fmaf(v2.y, sel2.y, dot);
        dot = fmaf(v2.z, sel2.z, dot); dot = fmaf(v2.w, sel2.w, dot);
        dot = wave_sum(dot);
        float rs = rsal[rbase + r], sv = sal[rbase + r], m = mask[rbase + r];
        float sim = dot * rs;
        float wr = (sim > 0.5f) ? (sim * m) : 0.f;
        float nm = m * (1.0f - fminf(fmaxf(sim, 0.f), 1.f));
        if (lane == 0) { mask[rbase + r] = nm; s_msal[r] = sv * nm; s_salL[r] = sv; }
        wsl += wr;
        acc0.x = fmaf(wr, v0.x, acc0.x); acc0.y = fmaf(wr, v0.y, acc0.y);
        acc0.z = fmaf(wr, v0.z, acc0.z); acc0.w = fmaf(wr, v0.w, acc0.w);
        acc1.x = fmaf(wr, v1.x, acc1.x); acc1.y = fmaf(wr, v1.y, acc1.y);
        acc1.z = fmaf(wr, v1.z, acc1.z); acc1.w = fmaf(wr, v1.w, acc1.w);
        acc2.x = fmaf(wr, v2.x, acc2.x); acc2.y = fmaf(wr, v2.y, acc2.y);
        acc2.z = fmaf(wr, v2.z, acc2.z); acc2.w = fmaf(wr, v2.w, acc2.w);
    }
    {
        float4* red = (float4*)(s_red + wave * D_);
        red[lane] = acc0; red[lane + 64] = acc1; red[lane + 128] = acc2;
        if (lane == 0) s_wsum[wave] = wsl;
    }
    __syncthreads();
    for (int c = tid; c < D_; c += THR) {
        float s = s_red[c] + s_red[D_ + c] + s_red[2*D_ + c] + s_red[3*D_ + c];
        num[((size_t)b * SLABS + g) * D_ + c] = s;
    }
    if (tid == 0) wsum[b*SLABS+g] = s_wsum[0] + s_wsum[1] + s_wsum[2] + s_wsum[3];
    if (wave == 0) {
        float v  = (lane < ROWS_PB) ? s_msal[lane] : -INFINITY;
        float sv = (lane < ROWS_PB) ? s_salL[lane] : 0.f;
        int   i  = (lane < ROWS_PB) ? (g * ROWS_PB + lane) : 0x7fffffff;
        #pragma unroll
        for (int off = 32; off; off >>= 1) {
            float ov = __shfl_xor(v, off);
            float osv = __shfl_xor(sv, off);
            int   oi = __shfl_xor(i, off);
            if (ov > v || (ov == v && oi < i)) { v = ov; sv = osv; i = oi; }
        }
        if (lane == 0) { argv[b*SLABS+g] = v; args[b*SLABS+g] = sv; argi[b*SLABS+g] = i; }
    }
}

// ---------------- last-resort mono kernel ----------------
__global__ __launch_bounds__(1024, 1)
void greedy_mono(const float* __restrict__ feat, float* __restrict__ out) {
    const int b = blockIdx.x, tid = threadIdx.x, wave = tid >> 6, lane = tid & 63;
    __shared__ float s_mask[N_], s_sal[N_], s_rsal[N_];
    __shared__ __align__(16) float s_sel[D_];
    __shared__ __align__(16) float s_red[16 * D_];
    __shared__ float s_wsum[16], s_argv[16];
    __shared__ int s_argi[16], s_idx;
    const float* fb = feat + (size_t)b * N_ * D_;
    {
        const int r0 = wave * 64;
        for (int r = r0; r < r0 + 64; ++r) {
            const float4* rp = (const float4*)(fb + (size_t)r * D_);
            float4 v0 = rp[lane], v1 = rp[lane+64], v2 = rp[lane+128];
            float ss = v0.x*v0.x+v0.y*v0.y+v0.z*v0.z+v0.w*v0.w
                     + v1.x*v1.x+v1.y*v1.y+v1.z*v1.z+v1.w*v1.w
                     + v2.x*v2.x+v2.y*v2.y+v2.z*v2.z+v2.w*v2.w;
            ss = wave_sum(ss);
            if (lane == 0) { float n = sqrtf(ss); s_sal[r]=n; s_rsal[r]=1.f/fmaxf(n,1e-12f); s_mask[r]=1.f; }
        }
    }
    __syncthreads();
    for (int t = 0; t < T_; ++t) {
        {
            float bv = s_sal[tid] * s_mask[tid]; int bi = tid;
            #pragma unroll
            for (int off = 32; off; off >>= 1) {
                float ov = __shfl_xor(bv, off); int oi = __shfl_xor(bi, off);
                if (ov > bv || (ov == bv && oi < bi)) { bv = ov; bi = oi; }
            }
            if (lane == 0) { s_argv[wave] = bv; s_argi[wave] = bi; }
        }
        __syncthreads();
        if (tid == 0) {
            float best = s_argv[0]; int besti = s_argi[0];
            #pragma unroll
            for (int w = 1; w < 16; ++w) {
                float v = s_argv[w]; int i = s_argi[w];
                if (v > best || (v == best && i < besti)) { best = v; besti = i; }
            }
            s_idx = besti;
        }
        __syncthreads();
        const int idx = s_idx;
        if (tid < D_) s_sel[tid] = fb[(size_t)idx*D_+tid] * (1.f/fmaxf(s_sal[idx],1e-12f));
        __syncthreads();
        const float4* selp = (const float4*)s_sel;
        float4 sel0 = selp[lane], sel1 = selp[lane+64], sel2 = selp[lane+128];
        float4 a0={0,0,0,0}, a1={0,0,0,0}, a2={0,0,0,0}; float wsl=0.f;
        const int r0 = wave * 64;
        for (int r = r0; r < r0 + 64; ++r) {
            const float4* rp = (const float4*)(fb + (size_t)r * D_);
            float4 v0 = rp[lane], v1 = rp[lane+64], v2 = rp[lane+128];
            float dot = 0.f;
            dot=fmaf(v0.x,sel0.x,dot); dot=fmaf(v0.y,sel0.y,dot); dot=fmaf(v0.z,sel0.z,dot); dot=fmaf(v0.w,sel0.w,dot);
            dot=fmaf(v1.x,sel1.x,dot); dot=fmaf(v1.y,sel1.y,dot); dot=fmaf(v1.z,sel1.z,dot); dot=fmaf(v1.w,sel1.w,dot);
            dot=fmaf(v2.x,sel2.x,dot); dot=fmaf(v2.y,sel2.y,dot); dot=fmaf(v2.z,sel2.z,dot); dot=fmaf(v2.w,sel2.w,dot);
            dot = wave_sum(dot);
            float sim = dot * s_rsal[r], m = s_mask[r];
            float wr = (sim > 0.5f) ? (sim * m) : 0.f;
            if (lane == 0) s_mask[r] = m * (1.f - fminf(fmaxf(sim,0.f),1.f));
            wsl += wr;
            a0.x=fmaf(wr,v0.x,a0.x); a0.y=fmaf(wr,v0.y,a0.y); a0.z=fmaf(wr,v0.z,a0.z); a0.w=fmaf(wr,v0.w,a0.w);
            a1.x=fmaf(wr,v1.x,a1.x); a1.y=fmaf(wr,v1.y,a1.y); a1.z=fmaf(wr,v1.z,a1.z); a1.w=fmaf(wr,v1.w,a1.w);
            a2.x=fmaf(wr,v2.x,a2.x); a2.y=fmaf(wr,v2.y,a2.y); a2.z=fmaf(wr,v2.z,a2.z); a2.w=fmaf(wr,v2.w,a2.w);
        }
        {
            float4* red = (float4*)(s_red + wave * D_);
            red[lane]=a0; red[lane+64]=a1; red[lane+128]=a2;
            if (lane == 0) s_wsum[wave] = wsl;
        }
        __syncthreads();
        if (tid < D_) {
            float s = 0.f, den = 0.f;
            #pragma unroll
            for (int w = 0; w < 16; ++w) { s += s_red[w*D_+tid]; den += s_wsum[w]; }
            out[((size_t)b*T_+t)*D_+tid] = s / (den + 1e-8f);
        }
        __syncthreads();
    }
}

extern "C" void kernel_launch(void* const* d_in, const int* in_sizes, int n_in,
                              void* d_out, int out_size, void* d_ws, size_t ws_size,
                              hipStream_t stream) {
    const float* feat = (const float*)d_in[0];
    float* out = (float*)d_out;
    (void)in_sizes; (void)n_in; (void)out_size;

    const size_t n_sal  = (size_t)B_ * N_;
    const size_t n_arg  = (size_t)B_ * SLABS;
    const size_t n_sel  = (size_t)B_ * D_;
    const size_t n_num  = (size_t)B_ * SLABS * D_;
    const size_t n_f16  = (size_t)B_ * N_ * D_;   // ushort elements

    const size_t need_scratch = (3*n_sal + 4*n_arg + n_sel + n_num) * sizeof(float);
    const size_t need_fp16    = need_scratch + n_f16 * sizeof(ushort) + 256;

    if (ws_size >= need_fp16) {
        char* base = (char*)d_ws;
        ushort* f16 = (ushort*)base;
        float* p = (float*)(base + ((n_f16 * sizeof(ushort) + 255) & ~(size_t)255));
        float* sal  = p;            p += n_sal;
        float* rsal = p;            p += n_sal;
        float* mask = p;            p += n_sal;
        float* argv = p;            p += n_arg;
        float* args = p;            p += n_arg;
        int*   argi = (int*)p;      p += n_arg;
        float* wsum = p;            p += n_arg;
        float* sel  = p;            p += n_sel;
        float* num  = p;            p += n_num;

        k_sal16<<<B_*SLABS, THR, 0, stream>>>(feat, f16, sal, rsal, mask, argv, args, argi);
        k_out<<<B_*4, 192, 0, stream>>>(feat, num, wsum, argv, args, argi, sel, out, -1);
        for (int t = 0; t < T_; ++t) {
            k_fused16<<<B_*SLABS, THR, 0, stream>>>(f16, sel, sal, rsal, mask,
                                                    num, wsum, argv, args, argi);
            k_out<<<B_*4, 192, 0, stream>>>(feat, num, wsum, argv, args, argi, sel, out, t);
        }
        return;
    }

    if (ws_size >= need_scratch) {
        float* p = (float*)d_ws;
        float* sal  = p;            p += n_sal;
        float* rsal = p;            p += n_sal;
        float* mask = p;            p += n_sal;
        float* argv = p;            p += n_arg;
        float* args = p;            p += n_arg;
        int*   argi = (int*)p;      p += n_arg;
        float* wsum = p;            p += n_arg;
        float* sel  = p;            p += n_sel;
        float* num  = p;            p += n_num;

        k_sal<<<B_*SLABS, THR, 0, stream>>>(feat, sal, rsal, mask, argv, args, argi);
        k_out<<<B_*4, 192, 0, stream>>>(feat, num, wsum, argv, args, argi, sel, out, -1);
        for (int t = 0; t < T_; ++t) {
            k_fused<<<B_*SLABS, THR, 0, stream>>>(feat, sel, sal, rsal, mask,
                                                  num, wsum, argv, args, argi);
            k_out<<<B_*4, 192, 0, stream>>>(feat, num, wsum, argv, args, argi, sel, out, t);
        }
        return;
    }

    greedy_mono<<<B_, 1024, 0, stream>>>(feat, out);
}